// Round 14
// baseline (242.190 us; speedup 1.0000x reference)
//
#include <hip/hip_runtime.h>
#include <hip/hip_bf16.h>
#include <math.h>

#define D_MODEL 1024
#define NUM_HEADS 16
#define DEPTH 64
#define BATCH 2
#define SEQ 2048
#define N_TOK (BATCH * SEQ)   // 4096

typedef short bf16x8 __attribute__((ext_vector_type(8)));
typedef _Float16 f16x8 __attribute__((ext_vector_type(8)));
typedef float f32x4  __attribute__((ext_vector_type(4)));
typedef unsigned short u16x8 __attribute__((ext_vector_type(8)));
typedef unsigned short u16x4 __attribute__((ext_vector_type(4)));
typedef unsigned int u32x4 __attribute__((ext_vector_type(4)));

__device__ __forceinline__ unsigned short f2b(float x) {
    return __builtin_bit_cast(unsigned short, __float2bfloat16(x));
}
__device__ __forceinline__ float b2f(unsigned short h) {
    return __builtin_bit_cast(float, (unsigned int)h << 16);
}
__device__ __forceinline__ unsigned short f2h(float x) {
    return __builtin_bit_cast(unsigned short, (_Float16)x);
}
__device__ __forceinline__ float h2f(unsigned short h) {
    return (float)__builtin_bit_cast(_Float16, h);
}

// permlane swap via BUILTINS (R13, validated bit-exact).
__device__ __forceinline__ void pl32_swap(unsigned int& x, unsigned int& y) {
    auto r = __builtin_amdgcn_permlane32_swap(x, y, false, false);
    x = (unsigned int)r[0]; y = (unsigned int)r[1];
}
__device__ __forceinline__ void pl16_swap(unsigned int& x, unsigned int& y) {
    auto r = __builtin_amdgcn_permlane16_swap(x, y, false, false);
    x = (unsigned int)r[0]; y = (unsigned int)r[1];
}

// Weight prep, one dispatch: wq/wk/wv/wo -> fp16.
__global__ __launch_bounds__(256) void prep_weights(
    const float* __restrict__ s0, const float* __restrict__ s1,
    const float* __restrict__ s2, const float* __restrict__ s3,
    unsigned short* __restrict__ f0, unsigned short* __restrict__ f1,
    unsigned short* __restrict__ f2, unsigned short* __restrict__ f3,
    int n8)
{
    const int i = blockIdx.x * 256 + threadIdx.x;
    if (i >= n8) return;
    const int which = blockIdx.y;
    const float* src = (which == 0) ? s0 : (which == 1) ? s1 : (which == 2) ? s2 : s3;
    unsigned short* dst = (which == 0) ? f0 : (which == 1) ? f1 : (which == 2) ? f2 : f3;
    const float4 a0 = ((const float4*)src)[2 * i];
    const float4 a1 = ((const float4*)src)[2 * i + 1];
    const float xs[8] = {a0.x, a0.y, a0.z, a0.w, a1.x, a1.y, a1.z, a1.w};
    u16x8 o;
    #pragma unroll
    for (int e = 0; e < 8; ++e) o[e] = f2h(xs[e]);
    *(u16x8*)&dst[(size_t)i * 8] = o;
}

// ---------------------------------------------------------------------------
// R17 qkv_gemm (validated 59-62us): 128x128 tile, 48 KB LDS (sA single-buf
// reg-staged fp32->f16; sB double-buf gload_lds), 2 barriers/K-step,
// 3 blocks/CU. (R18's 1-barrier/64KB variant dropped occupancy and
// regressed — occupancy beats barrier count at this operating point.)
// ---------------------------------------------------------------------------
__global__ __launch_bounds__(256, 3) void qkv_gemm(
    const float* __restrict__ Aq, const float* __restrict__ Ak,
    const float* __restrict__ Av,
    const unsigned short* __restrict__ Wq, const unsigned short* __restrict__ Wk,
    const unsigned short* __restrict__ Wv,
    const float* __restrict__ bq, const float* __restrict__ bk,
    const float* __restrict__ bv,
    void* __restrict__ Yq, void* __restrict__ Yk, void* __restrict__ Yvp)
{
    __shared__ unsigned short sA[128][64];      // single-buffered (reg-staged)
    __shared__ unsigned short sB[2][128][64];   // double-buffered (gload_lds)

    const int flat = (blockIdx.z * 32 + blockIdx.y) * 8 + blockIdx.x;
    const int swz  = (flat & 7) * 96 + (flat >> 3);      // 768 = 8*96, bijective
    const int bx = swz & 7;
    const int by = (swz >> 3) & 31;
    const int bz = swz >> 8;

    const float* Af = (bz == 0) ? Aq : (bz == 1) ? Ak : Av;
    const unsigned short* Bf = (bz == 0) ? Wq : (bz == 1) ? Wk : Wv;
    const float* bias = (bz == 0) ? bq : (bz == 1) ? bk : bv;
    const float scale = (bz == 0) ? 0.125f : 1.0f;
    const int mode = (bz == 2) ? 2 : 1;
    void* Yv = (bz == 0) ? Yq : (bz == 1) ? Yk : Yvp;

    const int tid  = threadIdx.x;
    const int wave = tid >> 6;
    const int lane = tid & 63;
    const int quad = lane >> 4;
    const int l16  = lane & 15;
    const int wm   = wave >> 1;          // 0..1 -> 64-row half
    const int wn   = wave & 1;           // 0..1 -> 64-col half

    const int j0 = bx * 128;
    const int i0 = by * 128;

    const int sc  = tid & 7;
    const int r32 = tid >> 3;            // 0..31

    f32x4 acc[4][4] = {};

    float4 fq[4][2];   // in-flight fp32 A slab (4 rows x 8 cols per thread)

    auto loadA = [&](int s) {
        const int k0 = s * 64;
        #pragma unroll
        for (int p = 0; p < 4; ++p) {
            const int row = p * 32 + r32;
            const int cg = (sc ^ (row & 7)) * 8;
            const float* srcp = &Af[(size_t)(i0 + row) * 1024 + k0 + cg];
            fq[p][0] = *(const float4*)srcp;
            fq[p][1] = *(const float4*)(srcp + 4);
        }
    };
    auto writeA = [&]() {
        #pragma unroll
        for (int p = 0; p < 4; ++p) {
            const int row = p * 32 + r32;
            const float xs[8] = {fq[p][0].x, fq[p][0].y, fq[p][0].z, fq[p][0].w,
                                 fq[p][1].x, fq[p][1].y, fq[p][1].z, fq[p][1].w};
            u16x8 o;
            #pragma unroll
            for (int e = 0; e < 8; ++e) o[e] = f2h(xs[e]);
            *(u16x8*)&sA[row][sc * 8] = o;
        }
    };
    auto stageB = [&](int buf, int s) {
        const int k0 = s * 64;
        #pragma unroll
        for (int p = 0; p < 4; ++p) {
            const int row = p * 32 + r32;
            const int cg = (sc ^ (row & 7)) * 8;
            __builtin_amdgcn_global_load_lds(
                (const __attribute__((address_space(1))) unsigned int*)
                    &Bf[(size_t)(j0 + row) * 1024 + k0 + cg],
                (__attribute__((address_space(3))) unsigned int*)&sB[buf][row][sc * 8],
                16, 0, 0);
        }
    };

    // prologue
    loadA(0);
    stageB(0, 0);
    writeA();                                              // waits fq (reg dep)
    __asm__ volatile("s_waitcnt vmcnt(0)" ::: "memory");   // B(0) landed
    __syncthreads();

    int cur = 0;
    for (int s = 0; s < 16; ++s) {
        if (s + 1 < 16) { loadA(s + 1); stageB(cur ^ 1, s + 1); }  // fly during compute

        #pragma unroll
        for (int ks = 0; ks < 2; ++ks) {
            f16x8 a[4], b[4];
            #pragma unroll
            for (int mt = 0; mt < 4; ++mt) {
                const int row = wm * 64 + mt * 16 + l16;
                const int c = (((ks * 4 + quad) ^ (row & 7))) * 8;
                a[mt] = *(const f16x8*)&sA[row][c];
            }
            #pragma unroll
            for (int nt = 0; nt < 4; ++nt) {
                const int row = wn * 64 + nt * 16 + l16;
                const int c = (((ks * 4 + quad) ^ (row & 7))) * 8;
                b[nt] = *(const f16x8*)&sB[cur][row][c];
            }
            #pragma unroll
            for (int mt = 0; mt < 4; ++mt)
                #pragma unroll
                for (int nt = 0; nt < 4; ++nt)
                    acc[mt][nt] = __builtin_amdgcn_mfma_f32_16x16x32_f16(a[mt], b[nt], acc[mt][nt], 0, 0, 0);
        }

        __syncthreads();                 // all waves done reading sA(s)/sB[cur]
        if (s + 1 < 16) {
            writeA();                    // sA <- slab s+1 (ds_write waits fq)
            __asm__ volatile("s_waitcnt vmcnt(0)" ::: "memory");  // B(s+1) landed
        }
        __syncthreads();                 // sA(s+1) + sB[cur^1] ready
        cur ^= 1;
    }

    float bvv[4];
    #pragma unroll
    for (int nt = 0; nt < 4; ++nt)
        bvv[nt] = bias[j0 + wn * 64 + nt * 16 + l16];

    #pragma unroll
    for (int mt = 0; mt < 4; ++mt) {
        const int ibase = i0 + wm * 64 + mt * 16 + quad * 4;  // + r
        #pragma unroll
        for (int nt = 0; nt < 4; ++nt) {
            const int j = j0 + wn * 64 + nt * 16 + l16;
            const int h = j >> 6, d = j & 63;
            if (mode == 1) {
                __hip_bfloat16* Y = (__hip_bfloat16*)Yv;
                #pragma unroll
                for (int r = 0; r < 4; ++r) {
                    const int i = ibase + r;
                    const int b = i >> 11, ss = i & (SEQ - 1);
                    Y[(((size_t)(b * NUM_HEADS + h) * SEQ) + ss) * DEPTH + d] =
                        __float2bfloat16((acc[mt][nt][r] + bvv[nt]) * scale);
                }
            } else {
                unsigned short* Y = (unsigned short*)Yv;
                const int b = ibase >> 11;
                u16x4 pack;
                #pragma unroll
                for (int r = 0; r < 4; ++r)
                    pack[r] = f2b((acc[mt][nt][r] + bvv[nt]) * scale);
                *(u16x4*)&Y[(((size_t)(b * NUM_HEADS + h) * DEPTH) + d) * SEQ
                            + (ibase & (SEQ - 1))] = pack;
            }
        }
    }
}

// ---------------------------------------------------------------------------
// R19 output projection (validated): fp16 2-MFMA, A = fp16 hi/lo, W = fp16.
// ---------------------------------------------------------------------------
__global__ __launch_bounds__(512, 2) void gemm_f16x2(
    const unsigned short* __restrict__ Ahi,  // fp16 hi [4096][1024]
    const unsigned short* __restrict__ Alo,  // fp16 lo
    const unsigned short* __restrict__ Bf,   // fp16 [1024][1024]
    const float* __restrict__ bias,
    float* __restrict__ Y,                   // fp32 flat [i][1024]
    float scale)
{
    __shared__ unsigned short sAh[128][64];
    __shared__ unsigned short sAl[128][64];
    __shared__ unsigned short sB [128][64];

    const int tid  = threadIdx.x;
    const int wave = tid >> 6;
    const int lane = tid & 63;
    const int quad = lane >> 4;
    const int l16  = lane & 15;
    const int wm   = wave >> 1;          // 0..3 -> 32-row strip
    const int wn   = wave & 1;           // 0..1 -> 64-col half

    const int j0 = blockIdx.x * 128;
    const int i0 = blockIdx.y * 128;

    const int sc  = tid & 7;
    const int r64 = tid >> 3;            // 0..63

    u16x8 preH[4], preL[2];

    auto prefetch = [&](int s) {
        const int k0 = s * 64;
        #pragma unroll
        for (int p = 0; p < 4; ++p) {
            const int row256 = p * 64 + r64;
            const bool isA = row256 < 128;
            const int row = isA ? row256 : row256 - 128;
            const int grow = (isA ? i0 : j0) + row;
            const int cg = (sc ^ (row & 7)) * 8;
            const size_t go = (size_t)grow * 1024 + k0 + cg;
            if (isA) {
                preH[p] = *(const u16x8*)&Ahi[go];
                preL[p] = *(const u16x8*)&Alo[go];
            } else {
                preH[p] = *(const u16x8*)&Bf[go];
            }
        }
    };

    prefetch(0);

    f32x4 acc[2][4] = {};

    for (int s = 0; s < 16; ++s) {
        __syncthreads();

        #pragma unroll
        for (int p = 0; p < 4; ++p) {
            const int row256 = p * 64 + r64;
            const bool isA = row256 < 128;
            const int row = isA ? row256 : row256 - 128;
            if (isA) {
                *(u16x8*)&sAh[row][sc * 8] = preH[p];
                *(u16x8*)&sAl[row][sc * 8] = preL[p];
            } else {
                *(u16x8*)&sB[row][sc * 8] = preH[p];
            }
        }
        __syncthreads();

        if (s + 1 < 16) prefetch(s + 1);

        #pragma unroll
        for (int ks = 0; ks < 2; ++ks) {
            f16x8 ah[2], al[2], b[4];
            #pragma unroll
            for (int mt = 0; mt < 2; ++mt) {
                const int row = wm * 32 + mt * 16 + l16;
                const int c = (((ks * 4 + quad) ^ (row & 7))) * 8;
                ah[mt] = *(const f16x8*)&sAh[row][c];
                al[mt] = *(const f16x8*)&sAl[row][c];
            }
            #pragma unroll
            for (int nt = 0; nt < 4; ++nt) {
                const int row = wn * 64 + nt * 16 + l16;
                const int c = (((ks * 4 + quad) ^ (row & 7))) * 8;
                b[nt] = *(const f16x8*)&sB[row][c];
            }
            #pragma unroll
            for (int mt = 0; mt < 2; ++mt)
                #pragma unroll
                for (int nt = 0; nt < 4; ++nt) {
                    acc[mt][nt] = __builtin_amdgcn_mfma_f32_16x16x32_f16(ah[mt], b[nt], acc[mt][nt], 0, 0, 0);
                    acc[mt][nt] = __builtin_amdgcn_mfma_f32_16x16x32_f16(al[mt], b[nt], acc[mt][nt], 0, 0, 0);
                }
        }
    }

    float bv[4];
    #pragma unroll
    for (int nt = 0; nt < 4; ++nt)
        bv[nt] = bias[j0 + wn * 64 + nt * 16 + l16];

    #pragma unroll
    for (int mt = 0; mt < 2; ++mt) {
        const int ibase = i0 + wm * 32 + mt * 16 + quad * 4;  // + r
        #pragma unroll
        for (int nt = 0; nt < 4; ++nt) {
            const int j = j0 + wn * 64 + nt * 16 + l16;
            #pragma unroll
            for (int r = 0; r < 4; ++r)
                Y[(size_t)(ibase + r) * 1024 + j] = (acc[mt][nt][r] + bv[nt]) * scale;
        }
    }
}

// ---------------------------------------------------------------------------
// bf16 MFMA flash attention v9 (R20): v8 + K/V staging via global_load_lds
// into XOR-swizzled [2][64][64] double buffer (the qkv-validated pattern:
// BANK_CONFLICT=0, bit-exact since R3).
// v8 had reg-staged ds_writes into pad-72 rows: 4 ds_write_b128/wave/tile on
// the LDS pipe, 4.19M conflict cycles (pitch-144B spreads imperfectly), and
// 2 barriers/tile. v9: 4 gload_lds/wave/tile (2 K + 2 V, coalesced 128B row
// segments — same segments v8 loaded), linear LDS dest + pre-swizzled global
// source (rule #21), swizzled fragment reads, ONE barrier per tile
// (stage buf^1 -> compute buf -> vmcnt(0)+sync). Occupancy unaffected
// (grid 512 = 2 blocks/CU; 32 KB LDS). Same bytes -> BIT-EXACT.
// ---------------------------------------------------------------------------
__global__ __launch_bounds__(256, 2) void flash_attn_mfma(
    const __hip_bfloat16* __restrict__ Qg,  // [BH][S][DEPTH], pre-scaled by 1/8
    const __hip_bfloat16* __restrict__ Kg,  // [BH][S][DEPTH]
    const __hip_bfloat16* __restrict__ Vg,  // [BH][DEPTH][S]
    unsigned short* __restrict__ OHi,       // [N_TOK][D_MODEL] fp16 hi
    unsigned short* __restrict__ OLo)       // [N_TOK][D_MODEL] fp16 lo
{
    __shared__ unsigned short Ks[2][64][64];
    __shared__ unsigned short Vt[2][64][64];

    const int tid  = threadIdx.x;
    const int wave = tid >> 6;
    const int lane = tid & 63;
    const int quad = lane >> 4;
    const int l16  = lane & 15;

    // XCD-chunk swizzle: 512 blocks = 8 XCDs x 64; each XCD gets 4 heads.
    const int flat = blockIdx.x;
    const int swz  = (flat & 7) * 64 + (flat >> 3);   // bijective on [0,512)
    const int bh = swz >> 4;
    const int q0 = (swz & 15) * 128;                  // 128-row q-span

    const unsigned short* Qu = (const unsigned short*)Qg + (size_t)bh * SEQ * DEPTH;
    const unsigned short* Ku = (const unsigned short*)Kg + (size_t)bh * SEQ * DEPTH;
    const unsigned short* Vu = (const unsigned short*)Vg + (size_t)bh * DEPTH * SEQ;

    const int qrowA = q0 + wave * 16 + l16;           // strip A
    const int qrowB = qrowA + 64;                     // strip B
    bf16x8 qfA[2], qfB[2];
    qfA[0] = *(const bf16x8*)&Qu[(size_t)qrowA * DEPTH + quad * 8];
    qfA[1] = *(const bf16x8*)&Qu[(size_t)qrowA * DEPTH + 32 + quad * 8];
    qfB[0] = *(const bf16x8*)&Qu[(size_t)qrowB * DEPTH + quad * 8];
    qfB[1] = *(const bf16x8*)&Qu[(size_t)qrowB * DEPTH + 32 + quad * 8];

    bf16x8 ones;
    #pragma unroll
    for (int e = 0; e < 8; ++e) ones[e] = (short)0x3F80;  // bf16 1.0

    f32x4 o_accA[4] = {}, o_accB[4] = {};
    f32x4 l_accA = {0.f, 0.f, 0.f, 0.f};
    f32x4 l_accB = {0.f, 0.f, 0.f, 0.f};

    const int lr8 = lane >> 3;   // 0..7 (row within wave's 8-row group)
    const int sc  = lane & 7;    // 16B chunk

    // Stage tile t into buffer buf: per wave 2 K + 2 V gload_lds (1 KB each,
    // linear dest = wave base + lane*16; source pre-swizzled per rule #21).
    auto stage = [&](int buf, int t) {
        const int k0 = t * 64;
        #pragma unroll
        for (int it = 0; it < 2; ++it) {
            const int rbase = it * 32 + wave * 8;
            const int row = rbase + lr8;
            const int cg = (sc ^ (row & 7)) * 8;
            __builtin_amdgcn_global_load_lds(
                (const __attribute__((address_space(1))) unsigned int*)
                    &Ku[(size_t)(k0 + row) * DEPTH + cg],
                (__attribute__((address_space(3))) unsigned int*)&Ks[buf][row][sc * 8],
                16, 0, 0);
            __builtin_amdgcn_global_load_lds(
                (const __attribute__((address_space(1))) unsigned int*)
                    &Vu[(size_t)row * SEQ + k0 + cg],
                (__attribute__((address_space(3))) unsigned int*)&Vt[buf][row][sc * 8],
                16, 0, 0);
        }
    };

    // In-register softmax pack (identical math, per strip).
    auto make_pf = [&](const f32x4 s[4], bf16x8 pf[2]) {
        unsigned int Wp[4][2];
        #pragma unroll
        for (int nt = 0; nt < 4; ++nt) {
            #pragma unroll
            for (int b = 0; b < 2; ++b) {
                const unsigned int lo = f2b(__expf(s[nt][2 * b]));
                const unsigned int hi = f2b(__expf(s[nt][2 * b + 1]));
                Wp[nt][b] = lo | (hi << 16);
            }
        }
        unsigned int pw[8];
        #pragma unroll
        for (int b = 0; b < 2; ++b) {
            unsigned int x = Wp[0][b], y = Wp[1][b];
            pl32_swap(x, y);
            pl16_swap(x, y);
            pw[b] = x; pw[2 + b] = y;
            x = Wp[2][b]; y = Wp[3][b];
            pl32_swap(x, y);
            pl16_swap(x, y);
            pw[4 + b] = x; pw[6 + b] = y;
        }
        u32x4 t0, t1;
        #pragma unroll
        for (int j = 0; j < 4; ++j) { t0[j] = pw[j]; t1[j] = pw[4 + j]; }
        pf[0] = __builtin_bit_cast(bf16x8, t0);   // P[l16][quad*8 + e]
        pf[1] = __builtin_bit_cast(bf16x8, t1);   // P[l16][32 + quad*8 + e]
    };

    // prologue: tile 0 into buffer 0
    stage(0, 0);
    __asm__ volatile("s_waitcnt vmcnt(0)" ::: "memory");
    __syncthreads();

    int cur = 0;
    for (int t = 0; t < 32; ++t) {
        if (t + 1 < 32) stage(cur ^ 1, t + 1);   // DMA flies during compute

        // ---- S^T = K Q^T for BOTH strips; each kf read feeds 2 MFMAs ----
        f32x4 sA[4], sB[4];
        #pragma unroll
        for (int nt = 0; nt < 4; ++nt) {
            sA[nt] = f32x4{0.f, 0.f, 0.f, 0.f};
            sB[nt] = f32x4{0.f, 0.f, 0.f, 0.f};
            const int row = nt * 16 + l16;
            bf16x8 kf0 = *(const bf16x8*)&Ks[cur][row][((quad ^ (row & 7))) * 8];
            sA[nt] = __builtin_amdgcn_mfma_f32_16x16x32_bf16(kf0, qfA[0], sA[nt], 0, 0, 0);
            sB[nt] = __builtin_amdgcn_mfma_f32_16x16x32_bf16(kf0, qfB[0], sB[nt], 0, 0, 0);
            bf16x8 kf1 = *(const bf16x8*)&Ks[cur][row][(((4 + quad) ^ (row & 7))) * 8];
            sA[nt] = __builtin_amdgcn_mfma_f32_16x16x32_bf16(kf1, qfA[1], sA[nt], 0, 0, 0);
            sB[nt] = __builtin_amdgcn_mfma_f32_16x16x32_bf16(kf1, qfB[1], sB[nt], 0, 0, 0);
        }

        // ---- P = exp(S) in-register, both strips ----
        bf16x8 pfA[2], pfB[2];
        make_pf(sA, pfA);
        make_pf(sB, pfB);

        // ---- O += P V; each vf read feeds 2 MFMAs ----
        #pragma unroll
        for (int nt = 0; nt < 4; ++nt) {
            const int row = nt * 16 + l16;
            bf16x8 vf0 = *(const bf16x8*)&Vt[cur][row][((quad ^ (row & 7))) * 8];
            o_accA[nt] = __builtin_amdgcn_mfma_f32_16x16x32_bf16(pfA[0], vf0, o_accA[nt], 0, 0, 0);
            o_accB[nt] = __builtin_amdgcn_mfma_f32_16x16x32_bf16(pfB[0], vf0, o_accB[nt], 0, 0, 0);
            bf16x8 vf1 = *(const bf16x8*)&Vt[cur][row][(((4 + quad) ^ (row & 7))) * 8];
            o_accA[nt] = __builtin_amdgcn_mfma_f32_16x16x32_bf16(pfA[1], vf1, o_accA[nt], 0, 0, 0);
            o_accB[nt] = __builtin_amdgcn_mfma_f32_16x16x32_bf16(pfB[1], vf1, o_accB[nt], 0, 0, 0);
        }
        l_accA = __builtin_amdgcn_mfma_f32_16x16x32_bf16(pfA[0], ones, l_accA, 0, 0, 0);
        l_accA = __builtin_amdgcn_mfma_f32_16x16x32_bf16(pfA[1], ones, l_accA, 0, 0, 0);
        l_accB = __builtin_amdgcn_mfma_f32_16x16x32_bf16(pfB[0], ones, l_accB, 0, 0, 0);
        l_accB = __builtin_amdgcn_mfma_f32_16x16x32_bf16(pfB[1], ones, l_accB, 0, 0, 0);

        if (t + 1 < 32) {
            __asm__ volatile("s_waitcnt vmcnt(0)" ::: "memory");  // next tile landed
            __syncthreads();   // one barrier per tile: all reads of cur done,
                               // all DMA into cur^1 done
        }
        cur ^= 1;
    }

    // ---- epilogue: normalize, split-store fp16 hi/lo (both strips) ----
    const int b = bh / NUM_HEADS;
    const int h = bh % NUM_HEADS;
    #pragma unroll
    for (int r = 0; r < 4; ++r) {
        const float invA = 1.f / l_accA[r];
        const float invB = 1.f / l_accB[r];
        const int rowA = q0 + wave * 16 + quad * 4 + r;
        const int rowB = rowA + 64;
        #pragma unroll
        for (int nt = 0; nt < 4; ++nt) {
            {
                const float o = o_accA[nt][r] * invA;
                const size_t idx = ((size_t)(b * SEQ + rowA)) * D_MODEL + h * DEPTH + nt * 16 + l16;
                const unsigned short hbits = f2h(o);
                OHi[idx] = hbits;
                OLo[idx] = f2h(o - h2f(hbits));
            }
            {
                const float o = o_accB[nt][r] * invB;
                const size_t idx = ((size_t)(b * SEQ + rowB)) * D_MODEL + h * DEPTH + nt * 16 + l16;
                const unsigned short hbits = f2h(o);
                OHi[idx] = hbits;
                OLo[idx] = f2h(o - h2f(hbits));
            }
        }
    }
}

// ---------------------------------------------------------------------------
extern "C" void kernel_launch(void* const* d_in, const int* in_sizes, int n_in,
                              void* d_out, int out_size, void* d_ws, size_t ws_size,
                              hipStream_t stream) {
    const float* q  = (const float*)d_in[0];
    const float* k  = (const float*)d_in[1];
    const float* v  = (const float*)d_in[2];
    const float* wq = (const float*)d_in[3];
    const float* bq = (const float*)d_in[4];
    const float* wk = (const float*)d_in[5];
    const float* bk = (const float*)d_in[6];
    const float* wv = (const float*)d_in[7];
    const float* bv = (const float*)d_in[8];
    const float* wo = (const float*)d_in[9];
    const float* bo = (const float*)d_in[10];
    float* out = (float*)d_out;

    // Workspace (50 MB):
    //  [0,  8) AoHi (fp16 hi, after attn)
    //  [8, 16) AoLo (fp16 lo)
    //  [16,18) WqF fp16  [18,20) WkF  [20,22) WvF  [22,24) WoF
    //  [26,34) Qh  [34,42) Kh  [42,50) Vh
    char* ws = (char*)d_ws;
    const size_t MB = 1024 * 1024;
    unsigned short* AoHi = (unsigned short*)(ws);
    unsigned short* AoLo = (unsigned short*)(ws + 8 * MB);
    unsigned short* WqF  = (unsigned short*)(ws + 16 * MB);
    unsigned short* WkF  = (unsigned short*)(ws + 18 * MB);
    unsigned short* WvF  = (unsigned short*)(ws + 20 * MB);
    unsigned short* WoF  = (unsigned short*)(ws + 22 * MB);
    __hip_bfloat16* Qh   = (__hip_bfloat16*)(ws + 26 * MB);
    __hip_bfloat16* Kh   = (__hip_bfloat16*)(ws + 34 * MB);
    __hip_bfloat16* Vh   = (__hip_bfloat16*)(ws + 42 * MB);

    const int nW8 = D_MODEL * D_MODEL / 8;   // 131072
    dim3 sb(256);

    prep_weights<<<dim3(nW8 / 256, 4), sb, 0, stream>>>(
        wq, wk, wv, wo, WqF, WkF, WvF, WoF, nW8);

    // All three projections in one dispatch (128x128 tile, fp32 inputs read
    // directly, fp16 convert fused into A staging; R17 2-barrier schedule).
    dim3 fblk(256);
    dim3 fgrid(D_MODEL / 128, N_TOK / 128, 3);   // 8 x 32 x 3 = 768 blocks
    qkv_gemm<<<fgrid, fblk, 0, stream>>>(
        q, k, v, WqF, WkF, WvF, bq, bk, bv, Qh, Kh, (void*)Vh);

    // attention -> Ao (fp16 hi/lo); 128 q rows per block
    dim3 ablk(256);
    dim3 agrid(BATCH * NUM_HEADS * (SEQ / 128));  // 512 blocks
    flash_attn_mfma<<<agrid, ablk, 0, stream>>>(Qh, Kh, Vh, AoHi, AoLo);

    // output projection (fp16 2-MFMA: A hi/lo x W single)
    dim3 oblk(512);
    dim3 ogrid(D_MODEL / 128, N_TOK / 128);  // 8 x 32 = 256 blocks
    gemm_f16x2<<<ogrid, oblk, 0, stream>>>(AoHi, AoLo, WoF, bo, out, 1.0f);
}

// Round 15
// 224.143 us; speedup vs baseline: 1.0805x; 1.0805x over previous
//
#include <hip/hip_runtime.h>
#include <hip/hip_bf16.h>
#include <math.h>

#define D_MODEL 1024
#define NUM_HEADS 16
#define DEPTH 64
#define BATCH 2
#define SEQ 2048
#define N_TOK (BATCH * SEQ)   // 4096

typedef short bf16x8 __attribute__((ext_vector_type(8)));
typedef _Float16 f16x8 __attribute__((ext_vector_type(8)));
typedef float f32x4  __attribute__((ext_vector_type(4)));
typedef unsigned short u16x8 __attribute__((ext_vector_type(8)));
typedef unsigned short u16x4 __attribute__((ext_vector_type(4)));
typedef unsigned int u32x4 __attribute__((ext_vector_type(4)));

__device__ __forceinline__ unsigned short f2b(float x) {
    return __builtin_bit_cast(unsigned short, __float2bfloat16(x));
}
__device__ __forceinline__ float b2f(unsigned short h) {
    return __builtin_bit_cast(float, (unsigned int)h << 16);
}
__device__ __forceinline__ unsigned short f2h(float x) {
    return __builtin_bit_cast(unsigned short, (_Float16)x);
}
__device__ __forceinline__ float h2f(unsigned short h) {
    return (float)__builtin_bit_cast(_Float16, h);
}

// permlane swap via BUILTINS (R13, validated bit-exact).
__device__ __forceinline__ void pl32_swap(unsigned int& x, unsigned int& y) {
    auto r = __builtin_amdgcn_permlane32_swap(x, y, false, false);
    x = (unsigned int)r[0]; y = (unsigned int)r[1];
}
__device__ __forceinline__ void pl16_swap(unsigned int& x, unsigned int& y) {
    auto r = __builtin_amdgcn_permlane16_swap(x, y, false, false);
    x = (unsigned int)r[0]; y = (unsigned int)r[1];
}

// Weight prep, one dispatch: wq/wk/wv/wo -> fp16.
__global__ __launch_bounds__(256) void prep_weights(
    const float* __restrict__ s0, const float* __restrict__ s1,
    const float* __restrict__ s2, const float* __restrict__ s3,
    unsigned short* __restrict__ f0, unsigned short* __restrict__ f1,
    unsigned short* __restrict__ f2, unsigned short* __restrict__ f3,
    int n8)
{
    const int i = blockIdx.x * 256 + threadIdx.x;
    if (i >= n8) return;
    const int which = blockIdx.y;
    const float* src = (which == 0) ? s0 : (which == 1) ? s1 : (which == 2) ? s2 : s3;
    unsigned short* dst = (which == 0) ? f0 : (which == 1) ? f1 : (which == 2) ? f2 : f3;
    const float4 a0 = ((const float4*)src)[2 * i];
    const float4 a1 = ((const float4*)src)[2 * i + 1];
    const float xs[8] = {a0.x, a0.y, a0.z, a0.w, a1.x, a1.y, a1.z, a1.w};
    u16x8 o;
    #pragma unroll
    for (int e = 0; e < 8; ++e) o[e] = f2h(xs[e]);
    *(u16x8*)&dst[(size_t)i * 8] = o;
}

// ---------------------------------------------------------------------------
// R17 qkv_gemm (validated 59-62us): 128x128 tile, 48 KB LDS (sA single-buf
// reg-staged fp32->f16; sB double-buf gload_lds), 2 barriers/K-step,
// 3 blocks/CU.
// ---------------------------------------------------------------------------
__global__ __launch_bounds__(256, 3) void qkv_gemm(
    const float* __restrict__ Aq, const float* __restrict__ Ak,
    const float* __restrict__ Av,
    const unsigned short* __restrict__ Wq, const unsigned short* __restrict__ Wk,
    const unsigned short* __restrict__ Wv,
    const float* __restrict__ bq, const float* __restrict__ bk,
    const float* __restrict__ bv,
    void* __restrict__ Yq, void* __restrict__ Yk, void* __restrict__ Yvp)
{
    __shared__ unsigned short sA[128][64];      // single-buffered (reg-staged)
    __shared__ unsigned short sB[2][128][64];   // double-buffered (gload_lds)

    const int flat = (blockIdx.z * 32 + blockIdx.y) * 8 + blockIdx.x;
    const int swz  = (flat & 7) * 96 + (flat >> 3);      // 768 = 8*96, bijective
    const int bx = swz & 7;
    const int by = (swz >> 3) & 31;
    const int bz = swz >> 8;

    const float* Af = (bz == 0) ? Aq : (bz == 1) ? Ak : Av;
    const unsigned short* Bf = (bz == 0) ? Wq : (bz == 1) ? Wk : Wv;
    const float* bias = (bz == 0) ? bq : (bz == 1) ? bk : bv;
    const float scale = (bz == 0) ? 0.125f : 1.0f;
    const int mode = (bz == 2) ? 2 : 1;
    void* Yv = (bz == 0) ? Yq : (bz == 1) ? Yk : Yvp;

    const int tid  = threadIdx.x;
    const int wave = tid >> 6;
    const int lane = tid & 63;
    const int quad = lane >> 4;
    const int l16  = lane & 15;
    const int wm   = wave >> 1;          // 0..1 -> 64-row half
    const int wn   = wave & 1;           // 0..1 -> 64-col half

    const int j0 = bx * 128;
    const int i0 = by * 128;

    const int sc  = tid & 7;
    const int r32 = tid >> 3;            // 0..31

    f32x4 acc[4][4] = {};

    float4 fq[4][2];   // in-flight fp32 A slab (4 rows x 8 cols per thread)

    auto loadA = [&](int s) {
        const int k0 = s * 64;
        #pragma unroll
        for (int p = 0; p < 4; ++p) {
            const int row = p * 32 + r32;
            const int cg = (sc ^ (row & 7)) * 8;
            const float* srcp = &Af[(size_t)(i0 + row) * 1024 + k0 + cg];
            fq[p][0] = *(const float4*)srcp;
            fq[p][1] = *(const float4*)(srcp + 4);
        }
    };
    auto writeA = [&]() {
        #pragma unroll
        for (int p = 0; p < 4; ++p) {
            const int row = p * 32 + r32;
            const float xs[8] = {fq[p][0].x, fq[p][0].y, fq[p][0].z, fq[p][0].w,
                                 fq[p][1].x, fq[p][1].y, fq[p][1].z, fq[p][1].w};
            u16x8 o;
            #pragma unroll
            for (int e = 0; e < 8; ++e) o[e] = f2h(xs[e]);
            *(u16x8*)&sA[row][sc * 8] = o;
        }
    };
    auto stageB = [&](int buf, int s) {
        const int k0 = s * 64;
        #pragma unroll
        for (int p = 0; p < 4; ++p) {
            const int row = p * 32 + r32;
            const int cg = (sc ^ (row & 7)) * 8;
            __builtin_amdgcn_global_load_lds(
                (const __attribute__((address_space(1))) unsigned int*)
                    &Bf[(size_t)(j0 + row) * 1024 + k0 + cg],
                (__attribute__((address_space(3))) unsigned int*)&sB[buf][row][sc * 8],
                16, 0, 0);
        }
    };

    // prologue
    loadA(0);
    stageB(0, 0);
    writeA();                                              // waits fq (reg dep)
    __asm__ volatile("s_waitcnt vmcnt(0)" ::: "memory");   // B(0) landed
    __syncthreads();

    int cur = 0;
    for (int s = 0; s < 16; ++s) {
        if (s + 1 < 16) { loadA(s + 1); stageB(cur ^ 1, s + 1); }  // fly during compute

        #pragma unroll
        for (int ks = 0; ks < 2; ++ks) {
            f16x8 a[4], b[4];
            #pragma unroll
            for (int mt = 0; mt < 4; ++mt) {
                const int row = wm * 64 + mt * 16 + l16;
                const int c = (((ks * 4 + quad) ^ (row & 7))) * 8;
                a[mt] = *(const f16x8*)&sA[row][c];
            }
            #pragma unroll
            for (int nt = 0; nt < 4; ++nt) {
                const int row = wn * 64 + nt * 16 + l16;
                const int c = (((ks * 4 + quad) ^ (row & 7))) * 8;
                b[nt] = *(const f16x8*)&sB[cur][row][c];
            }
            #pragma unroll
            for (int mt = 0; mt < 4; ++mt)
                #pragma unroll
                for (int nt = 0; nt < 4; ++nt)
                    acc[mt][nt] = __builtin_amdgcn_mfma_f32_16x16x32_f16(a[mt], b[nt], acc[mt][nt], 0, 0, 0);
        }

        __syncthreads();                 // all waves done reading sA(s)/sB[cur]
        if (s + 1 < 16) {
            writeA();                    // sA <- slab s+1 (ds_write waits fq)
            __asm__ volatile("s_waitcnt vmcnt(0)" ::: "memory");  // B(s+1) landed
        }
        __syncthreads();                 // sA(s+1) + sB[cur^1] ready
        cur ^= 1;
    }

    float bvv[4];
    #pragma unroll
    for (int nt = 0; nt < 4; ++nt)
        bvv[nt] = bias[j0 + wn * 64 + nt * 16 + l16];

    #pragma unroll
    for (int mt = 0; mt < 4; ++mt) {
        const int ibase = i0 + wm * 64 + mt * 16 + quad * 4;  // + r
        #pragma unroll
        for (int nt = 0; nt < 4; ++nt) {
            const int j = j0 + wn * 64 + nt * 16 + l16;
            const int h = j >> 6, d = j & 63;
            if (mode == 1) {
                __hip_bfloat16* Y = (__hip_bfloat16*)Yv;
                #pragma unroll
                for (int r = 0; r < 4; ++r) {
                    const int i = ibase + r;
                    const int b = i >> 11, ss = i & (SEQ - 1);
                    Y[(((size_t)(b * NUM_HEADS + h) * SEQ) + ss) * DEPTH + d] =
                        __float2bfloat16((acc[mt][nt][r] + bvv[nt]) * scale);
                }
            } else {
                unsigned short* Y = (unsigned short*)Yv;
                const int b = ibase >> 11;
                u16x4 pack;
                #pragma unroll
                for (int r = 0; r < 4; ++r)
                    pack[r] = f2b((acc[mt][nt][r] + bvv[nt]) * scale);
                *(u16x4*)&Y[(((size_t)(b * NUM_HEADS + h) * DEPTH) + d) * SEQ
                            + (ibase & (SEQ - 1))] = pack;
            }
        }
    }
}

// ---------------------------------------------------------------------------
// R21 output projection: SINGLE-A fp16, 1 MFMA per (mt,nt,ks).
// Error analysis: A single fp16 adds per-output error std ~4e-5 (5-sigma
// ~3.4e-4) on top of the validated W-fp16 rounding — vs threshold 5.6e-3.
// (bf16 single-A would be ~2.7e-3 — that's why the ORIGINAL needed hi/lo;
// fp16's 3 extra mantissa bits make the split unnecessary.)
// Same 512-thr 128x128 skeleton; 2 x 16KB LDS = 32KB; half the A traffic
// and half the MFMAs of R19's f16x2.
// ---------------------------------------------------------------------------
__global__ __launch_bounds__(512, 2) void gemm_f16o(
    const unsigned short* __restrict__ Af,   // fp16 [4096][1024] (attn out)
    const unsigned short* __restrict__ Bf,   // fp16 [1024][1024]
    const float* __restrict__ bias,
    float* __restrict__ Y,                   // fp32 flat [i][1024]
    float scale)
{
    __shared__ unsigned short sA[128][64];
    __shared__ unsigned short sB[128][64];

    const int tid  = threadIdx.x;
    const int wave = tid >> 6;
    const int lane = tid & 63;
    const int quad = lane >> 4;
    const int l16  = lane & 15;
    const int wm   = wave >> 1;          // 0..3 -> 32-row strip
    const int wn   = wave & 1;           // 0..1 -> 64-col half

    const int j0 = blockIdx.x * 128;
    const int i0 = blockIdx.y * 128;

    const int sc  = tid & 7;
    const int r64 = tid >> 3;            // 0..63

    u16x8 pre[4];

    auto prefetch = [&](int s) {
        const int k0 = s * 64;
        #pragma unroll
        for (int p = 0; p < 4; ++p) {
            const int row256 = p * 64 + r64;
            const bool isA = row256 < 128;
            const int row = isA ? row256 : row256 - 128;
            const int grow = (isA ? i0 : j0) + row;
            const int cg = (sc ^ (row & 7)) * 8;
            const size_t go = (size_t)grow * 1024 + k0 + cg;
            pre[p] = *(const u16x8*)&(isA ? Af : Bf)[go];
        }
    };

    prefetch(0);

    f32x4 acc[2][4] = {};

    for (int s = 0; s < 16; ++s) {
        __syncthreads();

        #pragma unroll
        for (int p = 0; p < 4; ++p) {
            const int row256 = p * 64 + r64;
            const bool isA = row256 < 128;
            const int row = isA ? row256 : row256 - 128;
            unsigned short (*dst)[64] = isA ? sA : sB;
            *(u16x8*)&dst[row][sc * 8] = pre[p];
        }
        __syncthreads();

        if (s + 1 < 16) prefetch(s + 1);

        #pragma unroll
        for (int ks = 0; ks < 2; ++ks) {
            f16x8 a[2], b[4];
            #pragma unroll
            for (int mt = 0; mt < 2; ++mt) {
                const int row = wm * 32 + mt * 16 + l16;
                const int c = (((ks * 4 + quad) ^ (row & 7))) * 8;
                a[mt] = *(const f16x8*)&sA[row][c];
            }
            #pragma unroll
            for (int nt = 0; nt < 4; ++nt) {
                const int row = wn * 64 + nt * 16 + l16;
                const int c = (((ks * 4 + quad) ^ (row & 7))) * 8;
                b[nt] = *(const f16x8*)&sB[row][c];
            }
            #pragma unroll
            for (int mt = 0; mt < 2; ++mt)
                #pragma unroll
                for (int nt = 0; nt < 4; ++nt)
                    acc[mt][nt] = __builtin_amdgcn_mfma_f32_16x16x32_f16(a[mt], b[nt], acc[mt][nt], 0, 0, 0);
        }
    }

    float bv[4];
    #pragma unroll
    for (int nt = 0; nt < 4; ++nt)
        bv[nt] = bias[j0 + wn * 64 + nt * 16 + l16];

    #pragma unroll
    for (int mt = 0; mt < 2; ++mt) {
        const int ibase = i0 + wm * 32 + mt * 16 + quad * 4;  // + r
        #pragma unroll
        for (int nt = 0; nt < 4; ++nt) {
            const int j = j0 + wn * 64 + nt * 16 + l16;
            #pragma unroll
            for (int r = 0; r < 4; ++r)
                Y[(size_t)(ibase + r) * 1024 + j] = (acc[mt][nt][r] + bv[nt]) * scale;
        }
    }
}

// ---------------------------------------------------------------------------
// bf16 MFMA flash attention v8 (R17-validated, REVERTED from v9): v6 LDS
// staging (reg-prefetch + ds_write, pad-72) + two q-strips per block.
// R20 lesson: v9's gload_lds+1-barrier variant eliminated bank conflicts
// but LOST the tile-deep register prefetch and regressed 56->64us —
// prefetch depth beats conflict elimination here. v8 restored verbatim.
// R21 change: epilogue stores SINGLE fp16 (no lo split) for the 1-MFMA
// output GEMM — strictly less work than v8's epilogue.
// ---------------------------------------------------------------------------
__global__ __launch_bounds__(256, 2) void flash_attn_mfma(
    const __hip_bfloat16* __restrict__ Qg,  // [BH][S][DEPTH], pre-scaled by 1/8
    const __hip_bfloat16* __restrict__ Kg,  // [BH][S][DEPTH]
    const __hip_bfloat16* __restrict__ Vg,  // [BH][DEPTH][S]
    unsigned short* __restrict__ Ao)        // [N_TOK][D_MODEL] fp16
{
    __shared__ unsigned short Ks[64][72];
    __shared__ unsigned short Vt[64][72];

    const int tid  = threadIdx.x;
    const int wave = tid >> 6;
    const int lane = tid & 63;
    const int quad = lane >> 4;
    const int l16  = lane & 15;

    // XCD-chunk swizzle: 512 blocks = 8 XCDs x 64; each XCD gets 4 heads.
    const int flat = blockIdx.x;
    const int swz  = (flat & 7) * 64 + (flat >> 3);   // bijective on [0,512)
    const int bh = swz >> 4;
    const int q0 = (swz & 15) * 128;                  // 128-row q-span

    const unsigned short* Qu = (const unsigned short*)Qg + (size_t)bh * SEQ * DEPTH;
    const unsigned short* Ku = (const unsigned short*)Kg + (size_t)bh * SEQ * DEPTH;
    const unsigned short* Vu = (const unsigned short*)Vg + (size_t)bh * DEPTH * SEQ;

    const int qrowA = q0 + wave * 16 + l16;           // strip A
    const int qrowB = qrowA + 64;                     // strip B
    bf16x8 qfA[2], qfB[2];
    qfA[0] = *(const bf16x8*)&Qu[(size_t)qrowA * DEPTH + quad * 8];
    qfA[1] = *(const bf16x8*)&Qu[(size_t)qrowA * DEPTH + 32 + quad * 8];
    qfB[0] = *(const bf16x8*)&Qu[(size_t)qrowB * DEPTH + quad * 8];
    qfB[1] = *(const bf16x8*)&Qu[(size_t)qrowB * DEPTH + 32 + quad * 8];

    bf16x8 ones;
    #pragma unroll
    for (int e = 0; e < 8; ++e) ones[e] = (short)0x3F80;  // bf16 1.0

    f32x4 o_accA[4] = {}, o_accB[4] = {};
    f32x4 l_accA = {0.f, 0.f, 0.f, 0.f};
    f32x4 l_accB = {0.f, 0.f, 0.f, 0.f};

    const int srow = tid >> 3;          // 0..31
    const int sc8  = (tid & 7) * 8;
    u16x8 kpre[2], vpre[2];
    #pragma unroll
    for (int it = 0; it < 2; ++it) {
        const int row = it * 32 + srow;
        kpre[it] = *(const u16x8*)&Ku[(size_t)row * DEPTH + sc8];
        vpre[it] = *(const u16x8*)&Vu[(size_t)row * SEQ + sc8];
    }

    // In-register softmax pack (identical math, per strip).
    auto make_pf = [&](const f32x4 s[4], bf16x8 pf[2]) {
        unsigned int Wp[4][2];
        #pragma unroll
        for (int nt = 0; nt < 4; ++nt) {
            #pragma unroll
            for (int b = 0; b < 2; ++b) {
                const unsigned int lo = f2b(__expf(s[nt][2 * b]));
                const unsigned int hi = f2b(__expf(s[nt][2 * b + 1]));
                Wp[nt][b] = lo | (hi << 16);
            }
        }
        unsigned int pw[8];
        #pragma unroll
        for (int b = 0; b < 2; ++b) {
            unsigned int x = Wp[0][b], y = Wp[1][b];
            pl32_swap(x, y);
            pl16_swap(x, y);
            pw[b] = x; pw[2 + b] = y;
            x = Wp[2][b]; y = Wp[3][b];
            pl32_swap(x, y);
            pl16_swap(x, y);
            pw[4 + b] = x; pw[6 + b] = y;
        }
        u32x4 t0, t1;
        #pragma unroll
        for (int j = 0; j < 4; ++j) { t0[j] = pw[j]; t1[j] = pw[4 + j]; }
        pf[0] = __builtin_bit_cast(bf16x8, t0);   // P[l16][quad*8 + e]
        pf[1] = __builtin_bit_cast(bf16x8, t1);   // P[l16][32 + quad*8 + e]
    };

    for (int t = 0; t < 32; ++t) {
        __syncthreads();  // prior tile's Ks/Vt reads complete (block-wide)

        #pragma unroll
        for (int it = 0; it < 2; ++it) {
            const int row = it * 32 + srow;
            *(u16x8*)&Ks[row][sc8] = kpre[it];
            *(u16x8*)&Vt[row][sc8] = vpre[it];
        }
        __syncthreads();

        if (t + 1 < 32) {
            const int k0 = (t + 1) * 64;
            #pragma unroll
            for (int it = 0; it < 2; ++it) {
                const int row = it * 32 + srow;
                kpre[it] = *(const u16x8*)&Ku[(size_t)(k0 + row) * DEPTH + sc8];
                vpre[it] = *(const u16x8*)&Vu[(size_t)row * SEQ + k0 + sc8];
            }
        }

        // ---- S^T = K Q^T for BOTH strips; each kf read feeds 2 MFMAs ----
        f32x4 sA[4], sB[4];
        #pragma unroll
        for (int nt = 0; nt < 4; ++nt) {
            sA[nt] = f32x4{0.f, 0.f, 0.f, 0.f};
            sB[nt] = f32x4{0.f, 0.f, 0.f, 0.f};
            bf16x8 kf0 = *(const bf16x8*)&Ks[nt * 16 + l16][quad * 8];
            sA[nt] = __builtin_amdgcn_mfma_f32_16x16x32_bf16(kf0, qfA[0], sA[nt], 0, 0, 0);
            sB[nt] = __builtin_amdgcn_mfma_f32_16x16x32_bf16(kf0, qfB[0], sB[nt], 0, 0, 0);
            bf16x8 kf1 = *(const bf16x8*)&Ks[nt * 16 + l16][32 + quad * 8];
            sA[nt] = __builtin_amdgcn_mfma_f32_16x16x32_bf16(kf1, qfA[1], sA[nt], 0, 0, 0);
            sB[nt] = __builtin_amdgcn_mfma_f32_16x16x32_bf16(kf1, qfB[1], sB[nt], 0, 0, 0);
        }

        // ---- P = exp(S) in-register, both strips ----
        bf16x8 pfA[2], pfB[2];
        make_pf(sA, pfA);
        make_pf(sB, pfB);

        // ---- O += P V; each vf read feeds 2 MFMAs ----
        #pragma unroll
        for (int nt = 0; nt < 4; ++nt) {
            bf16x8 vf0 = *(const bf16x8*)&Vt[nt * 16 + l16][quad * 8];
            o_accA[nt] = __builtin_amdgcn_mfma_f32_16x16x32_bf16(pfA[0], vf0, o_accA[nt], 0, 0, 0);
            o_accB[nt] = __builtin_amdgcn_mfma_f32_16x16x32_bf16(pfB[0], vf0, o_accB[nt], 0, 0, 0);
            bf16x8 vf1 = *(const bf16x8*)&Vt[nt * 16 + l16][32 + quad * 8];
            o_accA[nt] = __builtin_amdgcn_mfma_f32_16x16x32_bf16(pfA[1], vf1, o_accA[nt], 0, 0, 0);
            o_accB[nt] = __builtin_amdgcn_mfma_f32_16x16x32_bf16(pfB[1], vf1, o_accB[nt], 0, 0, 0);
        }
        l_accA = __builtin_amdgcn_mfma_f32_16x16x32_bf16(pfA[0], ones, l_accA, 0, 0, 0);
        l_accA = __builtin_amdgcn_mfma_f32_16x16x32_bf16(pfA[1], ones, l_accA, 0, 0, 0);
        l_accB = __builtin_amdgcn_mfma_f32_16x16x32_bf16(pfB[0], ones, l_accB, 0, 0, 0);
        l_accB = __builtin_amdgcn_mfma_f32_16x16x32_bf16(pfB[1], ones, l_accB, 0, 0, 0);
    }

    // ---- epilogue: normalize, single fp16 store (both strips) ----
    const int b = bh / NUM_HEADS;
    const int h = bh % NUM_HEADS;
    #pragma unroll
    for (int r = 0; r < 4; ++r) {
        const float invA = 1.f / l_accA[r];
        const float invB = 1.f / l_accB[r];
        const int rowA = q0 + wave * 16 + quad * 4 + r;
        const int rowB = rowA + 64;
        #pragma unroll
        for (int nt = 0; nt < 4; ++nt) {
            Ao[((size_t)(b * SEQ + rowA)) * D_MODEL + h * DEPTH + nt * 16 + l16] =
                f2h(o_accA[nt][r] * invA);
            Ao[((size_t)(b * SEQ + rowB)) * D_MODEL + h * DEPTH + nt * 16 + l16] =
                f2h(o_accB[nt][r] * invB);
        }
    }
}

// ---------------------------------------------------------------------------
extern "C" void kernel_launch(void* const* d_in, const int* in_sizes, int n_in,
                              void* d_out, int out_size, void* d_ws, size_t ws_size,
                              hipStream_t stream) {
    const float* q  = (const float*)d_in[0];
    const float* k  = (const float*)d_in[1];
    const float* v  = (const float*)d_in[2];
    const float* wq = (const float*)d_in[3];
    const float* bq = (const float*)d_in[4];
    const float* wk = (const float*)d_in[5];
    const float* bk = (const float*)d_in[6];
    const float* wv = (const float*)d_in[7];
    const float* bv = (const float*)d_in[8];
    const float* wo = (const float*)d_in[9];
    const float* bo = (const float*)d_in[10];
    float* out = (float*)d_out;

    // Workspace (50 MB):
    //  [0,  8) Ao (fp16, after attn)
    //  [16,18) WqF fp16  [18,20) WkF  [20,22) WvF  [22,24) WoF
    //  [26,34) Qh  [34,42) Kh  [42,50) Vh
    char* ws = (char*)d_ws;
    const size_t MB = 1024 * 1024;
    unsigned short* Ao   = (unsigned short*)(ws);
    unsigned short* WqF  = (unsigned short*)(ws + 16 * MB);
    unsigned short* WkF  = (unsigned short*)(ws + 18 * MB);
    unsigned short* WvF  = (unsigned short*)(ws + 20 * MB);
    unsigned short* WoF  = (unsigned short*)(ws + 22 * MB);
    __hip_bfloat16* Qh   = (__hip_bfloat16*)(ws + 26 * MB);
    __hip_bfloat16* Kh   = (__hip_bfloat16*)(ws + 34 * MB);
    __hip_bfloat16* Vh   = (__hip_bfloat16*)(ws + 42 * MB);

    const int nW8 = D_MODEL * D_MODEL / 8;   // 131072
    dim3 sb(256);

    prep_weights<<<dim3(nW8 / 256, 4), sb, 0, stream>>>(
        wq, wk, wv, wo, WqF, WkF, WvF, WoF, nW8);

    // All three projections in one dispatch (R17 2-barrier schedule).
    dim3 fblk(256);
    dim3 fgrid(D_MODEL / 128, N_TOK / 128, 3);   // 8 x 32 x 3 = 768 blocks
    qkv_gemm<<<fgrid, fblk, 0, stream>>>(
        q, k, v, WqF, WkF, WvF, bq, bk, bv, Qh, Kh, (void*)Vh);

    // attention -> Ao (single fp16); 128 q rows per block
    dim3 ablk(256);
    dim3 agrid(BATCH * NUM_HEADS * (SEQ / 128));  // 512 blocks
    flash_attn_mfma<<<agrid, ablk, 0, stream>>>(Qh, Kh, Vh, Ao);

    // output projection (fp16 single-A, 1 MFMA)
    dim3 oblk(512);
    dim3 ogrid(D_MODEL / 128, N_TOK / 128);  // 8 x 32 = 256 blocks
    gemm_f16o<<<ogrid, oblk, 0, stream>>>(Ao, WoF, bo, out, 1.0f);
}